// Round 14
// baseline (92.281 us; speedup 1.0000x reference)
//
#include <hip/hip_runtime.h>
#include <stdint.h>

typedef unsigned short u16;
typedef unsigned int u32;
typedef __attribute__((ext_vector_type(4))) float f32x4;
typedef __attribute__((ext_vector_type(4))) u16 u16x4;
typedef __attribute__((ext_vector_type(8))) __bf16 bf16x8;

__device__ __forceinline__ u16 f2bf(float f) {
  u32 u = __builtin_bit_cast(u32, f);
  u = (u + 0x7FFFu + ((u >> 16) & 1u)) >> 16;   // RNE
  return (u16)u;
}

__device__ __forceinline__ void gload_lds16(const void* g, void* l) {
  __builtin_amdgcn_global_load_lds(
      (const __attribute__((address_space(1))) void*)(uintptr_t)(g),
      (__attribute__((address_space(3))) void*)(u32)(uintptr_t)(l),
      16, 0, 0);
}

// ---- fused prep: x cvt (blocks 0..4095), w_attn^T (4096..7167), w_proj^T ----
__global__ __launch_bounds__(256) void k_prep(
    const float* __restrict__ x, u16* __restrict__ xbf,
    const float* __restrict__ wa, u16* __restrict__ wat,
    const float* __restrict__ wp, u16* __restrict__ wpt) {
  __shared__ float tile[32][33];
  const int bid = blockIdx.x, t = threadIdx.x;
  if (bid < 4096) {
    int i = bid * 256 + t;
    f32x4 v = ((const f32x4*)x)[i];
    u16x4 o = { f2bf(v.x), f2bf(v.y), f2bf(v.z), f2bf(v.w) };
    ((u16x4*)xbf)[i] = o;
    return;
  }
  const float* in;
  u16* out;
  int n0, k0, N;
  if (bid < 4096 + 3072) {
    int idx = bid - 4096;
    in = wa; out = wat; N = 3072;
    n0 = (idx % 96) * 32; k0 = (idx / 96) * 32;
  } else {
    int idx = bid - 7168;
    in = wp; out = wpt; N = 1024;
    n0 = (idx & 31) * 32; k0 = (idx >> 5) * 32;
  }
  int c = t & 31, r0 = t >> 5;
#pragma unroll
  for (int i = 0; i < 4; ++i)
    tile[r0 + i * 8][c] = in[(size_t)(k0 + r0 + i * 8) * N + n0 + c];
  __syncthreads();
  int on = t >> 3, ok = (t & 7) * 4;
  u16x4 o = { f2bf(tile[ok + 0][on]), f2bf(tile[ok + 1][on]),
              f2bf(tile[ok + 2][on]), f2bf(tile[ok + 3][on]) };
  *(u16x4*)&out[(size_t)(n0 + on) * 1024 + k0 + ok] = o;
}

// ---- k_kv: blocks 0..4095 = V^T tiles (f32->bf16), 4096..8191 = K cvt ----
__global__ __launch_bounds__(256) void k_kv(const float* __restrict__ present,
                                            u16* __restrict__ kbf,
                                            u16* __restrict__ vtw) {
  __shared__ float tile[32][33];
  const int bid = blockIdx.x, t = threadIdx.x;
  if (bid >= 4096) {
    int i = bid - 4096;
    size_t idx = (size_t)i * 256 + t;           // f32x4 index into K halves
    size_t b = idx >> 19, off = idx & ((1u << 19) - 1);
    f32x4 v = ((const f32x4*)present)[b * (1u << 20) + off];
    u16x4 o = { f2bf(v.x), f2bf(v.y), f2bf(v.z), f2bf(v.w) };
    ((u16x4*)kbf)[idx] = o;
    return;
  }
  int bh = bid >> 7, rem = bid & 127;
  int s0 = (rem >> 1) * 32, d0 = (rem & 1) * 32;
  int b = bh >> 4, h = bh & 15;
  const float* vsrc = present + (((size_t)(b * 2 + 1) * 16 + h) * 2048) * 64;
  u16* vdst = vtw + ((size_t)bh * 64) * 2048;
  int c = t & 31, r0 = t >> 5;
#pragma unroll
  for (int i = 0; i < 4; ++i)
    tile[r0 + i * 8][c] = vsrc[(size_t)(s0 + r0 + i * 8) * 64 + d0 + c];
  __syncthreads();
  int on = t >> 3, ok = (t & 7) * 4;
  u16x4 o = { f2bf(tile[ok + 0][on]), f2bf(tile[ok + 1][on]),
              f2bf(tile[ok + 2][on]), f2bf(tile[ok + 3][on]) };
  *(u16x4*)&vdst[(size_t)(d0 + on) * 2048 + s0 + ok] = o;
}

// ======== 256x192 BK=128 single-buffer GEMM for QKV (M=4096,N=3072,K=1024) ==
// 512 thr = 8 waves (4M x 2N), per-wave 64x96. Grid 16x16 = 256 = 1 block/CU.
// 8 K-steps (vs 16): per step {sync; stage 14 gloads; sync; 4x {frag reads,
// 24 MFMA}}. LDS 112 KB single-buffered; simplest race-free sync
// (__syncthreads only). Diagnostic fork vs R13: per-K-step overhead halves
// or byte-bound null. No setprio (m190: negative on lockstep).
__global__ __launch_bounds__(512, 1) void k_gemm256(
    const u16* __restrict__ A, const u16* __restrict__ Bt,
    const float* __restrict__ bias, u16* __restrict__ outq,
    float* __restrict__ outp) {
  __shared__ u16 a_lds[256 * 128];             // 64 KB, 256 B rows
  __shared__ u16 b_lds[192 * 128];             // 48 KB
  const int t = threadIdx.x;
  const int lane = t & 63, w = t >> 6;
  const int cc = lane & 15, g = lane >> 4;
  const int wr = w >> 1, wc = w & 1;           // 4M x 2N wave grid

  int f = blockIdx.y * 16 + blockIdx.x;        // 256 blocks = 1/CU
  int xcd = f & 7, idx = f >> 3;
  const int m0 = ((xcd >> 1) * 4 + (idx >> 3)) * 256;
  const int n0 = ((xcd & 1) * 8 + (idx & 7)) * 192;

  const int srow = t >> 4;                     // 0..31
  const int scolb = (t & 15) * 16;             // 0..240 within 256 B row
  const size_t pitch = 2048;                   // K*2 bytes

  auto stage = [&](int kt) {
#pragma unroll
    for (int i = 0; i < 8; ++i) {
      int row = i * 32 + srow;
      gload_lds16((const char*)A + (size_t)(m0 + row) * pitch + kt * 256 +
                      (scolb ^ ((row & 7) << 4)),
                  (char*)a_lds + row * 256 + scolb);
    }
#pragma unroll
    for (int i = 0; i < 6; ++i) {
      int row = i * 32 + srow;
      gload_lds16((const char*)Bt + (size_t)(n0 + row) * pitch + kt * 256 +
                      (scolb ^ ((row & 7) << 4)),
                  (char*)b_lds + row * 256 + scolb);
    }
  };

  f32x4 acc[4][6] = {};

  for (int kt = 0; kt < 8; ++kt) {
    __syncthreads();                           // prev tile fully consumed
    stage(kt);
    __syncthreads();                           // tile published (full drain)
#pragma unroll
    for (int kk = 0; kk < 4; ++kk) {
      bf16x8 af[4], bf_[6];
#pragma unroll
      for (int mf = 0; mf < 4; ++mf) {
        int row = wr * 64 + mf * 16 + cc;
        af[mf] = *(const bf16x8*)((const char*)a_lds + row * 256 +
                                  ((kk * 64 + g * 16) ^ ((row & 7) << 4)));
      }
#pragma unroll
      for (int nf = 0; nf < 6; ++nf) {
        int row = wc * 96 + nf * 16 + cc;
        bf_[nf] = *(const bf16x8*)((const char*)b_lds + row * 256 +
                                   ((kk * 64 + g * 16) ^ ((row & 7) << 4)));
      }
#pragma unroll
      for (int mf = 0; mf < 4; ++mf)
#pragma unroll
        for (int nf = 0; nf < 6; ++nf)
          acc[mf][nf] = __builtin_amdgcn_mfma_f32_16x16x32_bf16(
              af[mf], bf_[nf], acc[mf][nf], 0, 0, 0);
    }
  }

  float bv[6];
#pragma unroll
  for (int nf = 0; nf < 6; ++nf) bv[nf] = bias[n0 + wc * 96 + nf * 16 + cc];

#pragma unroll
  for (int mf = 0; mf < 4; ++mf)
#pragma unroll
    for (int nf = 0; nf < 6; ++nf) {
      int n = n0 + wc * 96 + nf * 16 + cc;
      int mb = m0 + wr * 64 + mf * 16 + g * 4;
      float v[4];
#pragma unroll
      for (int j = 0; j < 4; ++j) v[j] = acc[mf][nf][j] + bv[nf];
      if (n < 1024) {
#pragma unroll
        for (int j = 0; j < 4; ++j) outq[(size_t)(mb + j) * 1024 + n] = f2bf(v[j]);
      } else {
        int n2 = n - 1024;
        int kv = n2 >> 10; n2 &= 1023;
        int hh = n2 >> 6, d = n2 & 63;
        int bb = mb >> 11, ss = mb & 2047;
        float* pr = outp + ((((size_t)bb * 2 + kv) * 16 + hh) * 2048 + ss) * 64 + d;
#pragma unroll
        for (int j = 0; j < 4; ++j) pr[(size_t)j * 64] = v[j];
      }
    }
}

// ---------------- 128xBN tile MFMA GEMM (m97 structure) — proj only ----------
template <int EPI, int BN>
__global__ __launch_bounds__(256) void k_gemm(
    const u16* __restrict__ A, const u16* __restrict__ Bt,
    const float* __restrict__ bias, u16* __restrict__ outq,
    float* __restrict__ outp, int M, int N, int K) {
  __shared__ u16 a_lds[128 * 64];
  __shared__ u16 b_lds[BN * 64];
  const int t = threadIdx.x;
  const int lane = t & 63, w = t >> 6;

  int m0, n0;
  {
    constexpr int NXT = (EPI == 0) ? 24 : 16;
    constexpr int NCH = (EPI == 0) ? 12 : 8;
    int f = blockIdx.y * NXT + blockIdx.x;
    int xcd = f & 7, idx = f >> 3;
    int mt = (xcd >> 1) * 8 + idx / NCH;
    int nt = (xcd & 1) * NCH + idx % NCH;
    m0 = mt * 128;
    n0 = nt * BN;
  }

  const int srow = t >> 3;
  const int scb = (t & 7) * 16;
  const int ssw = scb ^ ((srow & 7) << 4);
  const size_t pitch = (size_t)K * 2;
  const char* aS = (const char*)A + (size_t)(m0 + srow) * pitch + ssw;
  const char* bS = (const char*)Bt + (size_t)(n0 + srow) * pitch + ssw;
  char* al = (char*)a_lds + t * 16;
  char* bl = (char*)b_lds + t * 16;
  const int wm = (w >> 1) * 64, wn = (w & 1) * (BN / 2);
  const int cc = lane & 15, g = lane >> 4;
  constexpr int NF = BN / 32;

  f32x4 acc[4][NF] = {};

  for (int kt = 0; kt < K; kt += 64) {
    __syncthreads();
#pragma unroll
    for (int i = 0; i < 4; ++i)
      gload_lds16(aS + (size_t)kt * 2 + (size_t)i * 32 * pitch, al + i * 4096);
#pragma unroll
    for (int i = 0; i < BN / 32; ++i)
      gload_lds16(bS + (size_t)kt * 2 + (size_t)i * 32 * pitch, bl + i * 4096);
    __syncthreads();
#pragma unroll
    for (int kk = 0; kk < 2; ++kk) {
      bf16x8 af[4], bf_[NF];
#pragma unroll
      for (int mf = 0; mf < 4; ++mf) {
        int row = wm + mf * 16 + cc;
        af[mf] = *(const bf16x8*)((const char*)a_lds + row * 128 +
                                  ((kk * 64 + g * 16) ^ ((row & 7) << 4)));
      }
#pragma unroll
      for (int nf = 0; nf < NF; ++nf) {
        int row = wn + nf * 16 + cc;
        bf_[nf] = *(const bf16x8*)((const char*)b_lds + row * 128 +
                                   ((kk * 64 + g * 16) ^ ((row & 7) << 4)));
      }
#pragma unroll
      for (int mf = 0; mf < 4; ++mf)
#pragma unroll
        for (int nf = 0; nf < NF; ++nf)
          acc[mf][nf] = __builtin_amdgcn_mfma_f32_16x16x32_bf16(
              af[mf], bf_[nf], acc[mf][nf], 0, 0, 0);
    }
  }

  float bv[NF];
#pragma unroll
  for (int nf = 0; nf < NF; ++nf) bv[nf] = bias[n0 + wn + nf * 16 + cc];

#pragma unroll
  for (int mf = 0; mf < 4; ++mf)
#pragma unroll
    for (int nf = 0; nf < NF; ++nf) {
      int n = n0 + wn + nf * 16 + cc;
      int mb = m0 + wm + mf * 16 + g * 4;
      float v[4];
#pragma unroll
      for (int j = 0; j < 4; ++j) v[j] = acc[mf][nf][j] + bv[nf];
      if (EPI == 1) {
#pragma unroll
        for (int j = 0; j < 4; ++j) outp[(size_t)(mb + j) * N + n] = v[j];
      } else if (n < 1024) {
#pragma unroll
        for (int j = 0; j < 4; ++j) outq[(size_t)(mb + j) * 1024 + n] = f2bf(v[j]);
      } else {
        int n2 = n - 1024;
        int kv = n2 >> 10; n2 &= 1023;
        int hh = n2 >> 6, d = n2 & 63;
        int bb = mb >> 11, ss = mb & 2047;
        float* pr = outp + ((((size_t)bb * 2 + kv) * 16 + hh) * 2048 + ss) * 64 + d;
#pragma unroll
        for (int j = 0; j < 4; ++j) pr[(size_t)j * 64] = v[j];
      }
    }
}

// ---------------- fused sparse attention v3 ----------------
__global__ __launch_bounds__(256) void k_attn(
    const u16* __restrict__ qws, const u16* __restrict__ kbf,
    const u16* __restrict__ vtw, u16* __restrict__ hws) {
  const int qb = blockIdx.x, h = blockIdx.y, b = blockIdx.z;
  const int t = threadIdx.x, lane = t & 63, w = t >> 6;
  const int cc = lane & 15, g = lane >> 4;

  __shared__ u16 k_lds[256 * 64];      // [256 keys][128 B], XOR-swizzled
  __shared__ u16 p_lds[4][32 * 72];    // per-wave P [32 q][144 B]
  __shared__ float rsum[4][32];

  const char* kh = (const char*)kbf + (size_t)(b * 16 + h) * (2048 * 128);
  const char* vh = (const char*)vtw + (size_t)(b * 16 + h) * (64 * 4096);

  {
    int rr = t >> 3, seg = (t & 7) * 16;
#pragma unroll
    for (int i = 0; i < 8; ++i) {
      int r = i * 32 + rr;
      int i2 = r - 128;
      int gr = (r < 128) ? (qb * 128 + r) : ((i2 >> 3) * 128 + 120 + (i2 & 7));
      gload_lds16(kh + (size_t)gr * 128 + (seg ^ ((r & 7) << 4)),
                  (char*)k_lds + i * 4096 + t * 16);
    }
  }

  bf16x8 qf_[2][2];
  {
    const char* qsrc = (const char*)qws +
        (size_t)(b * 2048 + qb * 128 + w * 32 + cc) * 2048 + h * 128 + g * 16;
#pragma unroll
    for (int qf = 0; qf < 2; ++qf)
#pragma unroll
      for (int kk = 0; kk < 2; ++kk)
        qf_[qf][kk] = *(const bf16x8*)(qsrc + (size_t)qf * 16 * 2048 + kk * 64);
  }
  __syncthreads();

  const int nsum = 8 * qb;
  f32x4 o_[2][4] = {};
  float lsum[2] = { 0.f, 0.f };

#pragma unroll 2
  for (int ch = 0; ch < 4; ++ch) {
    f32x4 s[4][2] = {};
#pragma unroll
    for (int kf2 = 0; kf2 < 4; ++kf2) {
      int row = ch * 64 + kf2 * 16 + cc;
      const char* kr = (const char*)k_lds + row * 128;
#pragma unroll
      for (int kk = 0; kk < 2; ++kk) {
        bf16x8 kfr = *(const bf16x8*)(kr + ((kk * 64 + g * 16) ^ ((cc & 7) << 4)));
#pragma unroll
        for (int qf = 0; qf < 2; ++qf)
          s[kf2][qf] = __builtin_amdgcn_mfma_f32_16x16x32_bf16(
              kfr, qf_[qf][kk], s[kf2][qf], 0, 0, 0);
      }
    }
#pragma unroll
    for (int qf = 0; qf < 2; ++qf) {
      int q_local = w * 32 + qf * 16 + cc;
#pragma unroll
      for (int kf2 = 0; kf2 < 4; ++kf2) {
#pragma unroll
        for (int j = 0; j < 4; ++j) {
          int key = ch * 64 + kf2 * 16 + g * 4 + j;
          bool vis = (key < 128) ? (key <= q_local) : (key - 128 < nsum);
          float p = vis ? exp2f(s[kf2][qf][j] * 0.180336884f) : 0.f;
          s[kf2][qf][j] = p;
          lsum[qf] += p;
        }
        u16x4 pw = { f2bf(s[kf2][qf][0]), f2bf(s[kf2][qf][1]),
                     f2bf(s[kf2][qf][2]), f2bf(s[kf2][qf][3]) };
        *(u16x4*)&p_lds[w][(qf * 16 + cc) * 72 + kf2 * 16 + g * 4] = pw;
      }
    }
#pragma unroll
    for (int kk = 0; kk < 2; ++kk) {
      bf16x8 pa[2], vb[4];
#pragma unroll
      for (int mf = 0; mf < 2; ++mf)
        pa[mf] = *(const bf16x8*)((const char*)p_lds[w] +
                                  (mf * 16 + cc) * 144 + kk * 64 + g * 16);
      int cb = (ch < 2) ? (qb * 256 + ch * 128 + kk * 64 + g * 16)
                        : (((ch - 2) * 8 + kk * 4 + g) * 256 + 240);
#pragma unroll
      for (int nf = 0; nf < 4; ++nf)
        vb[nf] = *(const bf16x8*)(vh + (size_t)(nf * 16 + cc) * 4096 + cb);
#pragma unroll
      for (int mf = 0; mf < 2; ++mf)
#pragma unroll
        for (int nf = 0; nf < 4; ++nf)
          o_[mf][nf] = __builtin_amdgcn_mfma_f32_16x16x32_bf16(pa[mf], vb[nf],
                                                               o_[mf][nf], 0, 0, 0);
    }
  }

#pragma unroll
  for (int qf = 0; qf < 2; ++qf) {
    float sum = lsum[qf];
    sum += __shfl_xor(sum, 16);
    sum += __shfl_xor(sum, 32);
    if (g == 0) rsum[w][qf * 16 + cc] = sum;
  }
#pragma unroll
  for (int mf = 0; mf < 2; ++mf)
#pragma unroll
    for (int j = 0; j < 4; ++j) {
      float inv = 1.0f / rsum[w][mf * 16 + g * 4 + j];
      size_t row = (size_t)(b * 2048 + qb * 128 + w * 32 + mf * 16 + g * 4 + j);
#pragma unroll
      for (int nf = 0; nf < 4; ++nf)
        hws[row * 1024 + h * 64 + nf * 16 + cc] = f2bf(o_[mf][nf][j] * inv);
    }
}

extern "C" void kernel_launch(void* const* d_in, const int* in_sizes, int n_in,
                              void* d_out, int out_size, void* d_ws, size_t ws_size,
                              hipStream_t stream) {
  const float* x      = (const float*)d_in[0];  // [2,2048,1024]
  const float* w_attn = (const float*)d_in[1];  // [1024,3072]
  const float* b_attn = (const float*)d_in[2];  // [3072]
  const float* w_proj = (const float*)d_in[3];  // [1024,1024]
  const float* b_proj = (const float*)d_in[4];  // [1024]
  float* h_out   = (float*)d_out;               // 4,194,304 f32
  float* present = (float*)d_out + 4194304;     // [2][2][16][2048][64] f32

  char* ws = (char*)d_ws;
  u16* xbf = (u16*)(ws);                        // 8 MB  [4096][1024] bf16
  u16* qws = (u16*)(ws + (8u << 20));           // 8 MB  [4096][1024] bf16
  u16* wat = (u16*)(ws + (16u << 20));          // 6 MB  [3072][1024] bf16
  u16* wpt = (u16*)(ws + (22u << 20));          // 2 MB  [1024][1024] bf16
  u16* kbf = (u16*)(ws + (24u << 20));          // 8 MB  [2][16][2048][64] bf16
  u16* vtw = (u16*)(ws + (32u << 20));          // 8 MB  [2][16][64][2048] bf16
  u16* hws = xbf;                               // reuse (x dead after QKV GEMM)

  k_prep<<<8192, 256, 0, stream>>>(x, xbf, w_attn, wat, w_proj, wpt);
  k_gemm256<<<dim3(16, 16), 512, 0, stream>>>(xbf, wat, b_attn, qws, present);
  k_kv<<<8192, 256, 0, stream>>>(present, kbf, vtw);
  k_attn<<<dim3(16, 16, 2), 256, 0, stream>>>(qws, kbf, vtw, hws);
  k_gemm<1, 64><<<dim3(16, 32), 256, 0, stream>>>(hws, wpt, b_proj, nullptr,
                                                  h_out, 4096, 1024, 1024);
}

// Round 15
// 88.261 us; speedup vs baseline: 1.0455x; 1.0455x over previous
//
#include <hip/hip_runtime.h>
#include <stdint.h>

typedef unsigned short u16;
typedef unsigned int u32;
typedef __attribute__((ext_vector_type(4))) float f32x4;
typedef __attribute__((ext_vector_type(4))) u16 u16x4;
typedef __attribute__((ext_vector_type(8))) __bf16 bf16x8;

__device__ __forceinline__ u16 f2bf(float f) {
  u32 u = __builtin_bit_cast(u32, f);
  u = (u + 0x7FFFu + ((u >> 16) & 1u)) >> 16;   // RNE
  return (u16)u;
}

__device__ __forceinline__ void gload_lds16(const void* g, void* l) {
  __builtin_amdgcn_global_load_lds(
      (const __attribute__((address_space(1))) void*)(uintptr_t)(g),
      (__attribute__((address_space(3))) void*)(u32)(uintptr_t)(l),
      16, 0, 0);
}

// ---- fused prep: x cvt (blocks 0..4095), w_attn^T (4096..7167), w_proj^T ----
__global__ __launch_bounds__(256) void k_prep(
    const float* __restrict__ x, u16* __restrict__ xbf,
    const float* __restrict__ wa, u16* __restrict__ wat,
    const float* __restrict__ wp, u16* __restrict__ wpt) {
  __shared__ float tile[32][33];
  const int bid = blockIdx.x, t = threadIdx.x;
  if (bid < 4096) {
    int i = bid * 256 + t;
    f32x4 v = ((const f32x4*)x)[i];
    u16x4 o = { f2bf(v.x), f2bf(v.y), f2bf(v.z), f2bf(v.w) };
    ((u16x4*)xbf)[i] = o;
    return;
  }
  const float* in;
  u16* out;
  int n0, k0, N;
  if (bid < 4096 + 3072) {
    int idx = bid - 4096;
    in = wa; out = wat; N = 3072;
    n0 = (idx % 96) * 32; k0 = (idx / 96) * 32;
  } else {
    int idx = bid - 7168;
    in = wp; out = wpt; N = 1024;
    n0 = (idx & 31) * 32; k0 = (idx >> 5) * 32;
  }
  int c = t & 31, r0 = t >> 5;
#pragma unroll
  for (int i = 0; i < 4; ++i)
    tile[r0 + i * 8][c] = in[(size_t)(k0 + r0 + i * 8) * N + n0 + c];
  __syncthreads();
  int on = t >> 3, ok = (t & 7) * 4;
  u16x4 o = { f2bf(tile[ok + 0][on]), f2bf(tile[ok + 1][on]),
              f2bf(tile[ok + 2][on]), f2bf(tile[ok + 3][on]) };
  *(u16x4*)&out[(size_t)(n0 + on) * 1024 + k0 + ok] = o;
}

// ---- k_kv: blocks 0..4095 = V^T tiles (f32->bf16), 4096..8191 = K cvt ----
__global__ __launch_bounds__(256) void k_kv(const float* __restrict__ present,
                                            u16* __restrict__ kbf,
                                            u16* __restrict__ vtw) {
  __shared__ float tile[32][33];
  const int bid = blockIdx.x, t = threadIdx.x;
  if (bid >= 4096) {
    int i = bid - 4096;
    size_t idx = (size_t)i * 256 + t;           // f32x4 index into K halves
    size_t b = idx >> 19, off = idx & ((1u << 19) - 1);
    f32x4 v = ((const f32x4*)present)[b * (1u << 20) + off];
    u16x4 o = { f2bf(v.x), f2bf(v.y), f2bf(v.z), f2bf(v.w) };
    ((u16x4*)kbf)[idx] = o;
    return;
  }
  int bh = bid >> 7, rem = bid & 127;
  int s0 = (rem >> 1) * 32, d0 = (rem & 1) * 32;
  int b = bh >> 4, h = bh & 15;
  const float* vsrc = present + (((size_t)(b * 2 + 1) * 16 + h) * 2048) * 64;
  u16* vdst = vtw + ((size_t)bh * 64) * 2048;
  int c = t & 31, r0 = t >> 5;
#pragma unroll
  for (int i = 0; i < 4; ++i)
    tile[r0 + i * 8][c] = vsrc[(size_t)(s0 + r0 + i * 8) * 64 + d0 + c];
  __syncthreads();
  int on = t >> 3, ok = (t & 7) * 4;
  u16x4 o = { f2bf(tile[ok + 0][on]), f2bf(tile[ok + 1][on]),
              f2bf(tile[ok + 2][on]), f2bf(tile[ok + 3][on]) };
  *(u16x4*)&vdst[(size_t)(d0 + on) * 2048 + s0 + ok] = o;
}

// ======== 256x192 fine-interleave 4-phase GEMM (M=4096,N=3072,K=1024) =======
// 512 thr = 8 waves. Phase q computes GLOBAL rows q*64 (waves tile 64x192 as
// 2 row-subbands x 4 col-groups) so A-half1 untouched before phase 2 by ANY
// wave -> counted cross-wave-safe waits. Per phase: {1 half-tile stage issue |
// ds_read 4-10 b128 -> BAR -> lgkm(0)+schedbar -> setprio 12 MFMA -> BAR}.
// Ledger (per-thread sim, steady invariant O={next.A1:2}):
//   q0: +B(3)  O=5 ; q1: +A0(2) O=7, exit vmcnt(5)+BAR (publishes this A1)
//   q2: +A1(2) O=7 ; q3: exit vmcnt(2)+BAR (publishes next B+A0, next A1 flys)
// All fences single asm w/ memory clobber; sched_barrier(0) after lgkm (r18).
__global__ __launch_bounds__(512, 1) void k_gemm256(
    const u16* __restrict__ A, const u16* __restrict__ Bt,
    const float* __restrict__ bias, u16* __restrict__ outq,
    float* __restrict__ outp) {
  __shared__ u16 a_lds[2][256 * 64];
  __shared__ u16 b_lds[2][192 * 64];
  const int t = threadIdx.x;
  const int lane = t & 63, w = t >> 6;
  const int cc = lane & 15, g = lane >> 4;
  const int wr2 = w >> 2, wc = w & 3;         // row-subband, col-group

  int f = blockIdx.y * 16 + blockIdx.x;       // 256 blocks = 1/CU
  int xcd = f & 7, idx = f >> 3;
  const int m0 = ((xcd >> 1) * 4 + (idx >> 3)) * 256;
  const int n0 = ((xcd & 1) * 8 + (idx & 7)) * 192;

  const int srow = t >> 3;                    // 0..63
  const int scolb = (t & 7) * 16;
  const size_t pitch = 2048;                  // K*2 bytes

  auto stageB = [&](int bi, int kt) {
#pragma unroll
    for (int i = 0; i < 3; ++i) {
      int row = i * 64 + srow;
      gload_lds16((const char*)Bt + (size_t)(n0 + row) * pitch + kt * 128 +
                      (scolb ^ ((row & 7) << 4)),
                  (char*)b_lds[bi] + row * 128 + scolb);
    }
  };
  auto stageA = [&](int bi, int kt, int half) {
#pragma unroll
    for (int i = 0; i < 2; ++i) {
      int row = half * 128 + i * 64 + srow;
      gload_lds16((const char*)A + (size_t)(m0 + row) * pitch + kt * 128 +
                      (scolb ^ ((row & 7) << 4)),
                  (char*)a_lds[bi] + row * 128 + scolb);
    }
  };

  f32x4 acc[8][3] = {};
  bf16x8 bfr[3][2];

  // prologue: stage tile 0 fully, full drain once
  stageB(0, 0);
  stageA(0, 0, 0);
  stageA(0, 0, 1);
  asm volatile("s_waitcnt vmcnt(0)\n\ts_barrier" ::: "memory");

  for (int kt = 0; kt < 16; ++kt) {
    const int bi = kt & 1, nx = bi ^ 1;
#pragma unroll
    for (int q = 0; q < 4; ++q) {
      // --- stage issue (one half-tile) ---
      if (kt < 15) {
        if (q == 0) stageB(nx, kt + 1);
        else if (q == 1) stageA(nx, kt + 1, 0);
        else if (q == 2) stageA(nx, kt + 1, 1);
      }
      // --- ds_read: B-frags once per tile, A-frags per phase ---
      if (q == 0) {
#pragma unroll
        for (int nf = 0; nf < 3; ++nf) {
          int row = wc * 48 + nf * 16 + cc;
#pragma unroll
          for (int kk = 0; kk < 2; ++kk)
            bfr[nf][kk] =
                *(const bf16x8*)((const char*)b_lds[bi] + row * 128 +
                                 ((kk * 64 + g * 16) ^ ((row & 7) << 4)));
        }
      }
      bf16x8 af[2][2];
#pragma unroll
      for (int mf = 0; mf < 2; ++mf) {
        int row = q * 64 + wr2 * 32 + mf * 16 + cc;
#pragma unroll
        for (int kk = 0; kk < 2; ++kk)
          af[mf][kk] = *(const bf16x8*)((const char*)a_lds[bi] + row * 128 +
                                        ((kk * 64 + g * 16) ^ ((row & 7) << 4)));
      }
      asm volatile("s_barrier" ::: "memory");            // phase-entry sync
      asm volatile("s_waitcnt lgkmcnt(0)" ::: "memory");
      __builtin_amdgcn_sched_barrier(0);                 // rule 18
      __builtin_amdgcn_s_setprio(1);
#pragma unroll
      for (int mf = 0; mf < 2; ++mf)
#pragma unroll
        for (int nf = 0; nf < 3; ++nf)
#pragma unroll
          for (int kk = 0; kk < 2; ++kk)
            acc[q * 2 + mf][nf] = __builtin_amdgcn_mfma_f32_16x16x32_bf16(
                af[mf][kk], bfr[nf][kk], acc[q * 2 + mf][nf], 0, 0, 0);
      __builtin_amdgcn_s_setprio(0);
      // --- phase-exit fence ---
      if (q == 1)
        asm volatile("s_waitcnt vmcnt(5)\n\ts_barrier" ::: "memory");
      else if (q == 3)
        asm volatile("s_waitcnt vmcnt(2)\n\ts_barrier" ::: "memory");
      else
        asm volatile("s_barrier" ::: "memory");
    }
  }

  float bv[3];
#pragma unroll
  for (int nf = 0; nf < 3; ++nf) bv[nf] = bias[n0 + wc * 48 + nf * 16 + cc];

#pragma unroll
  for (int a = 0; a < 8; ++a)
#pragma unroll
    for (int nf = 0; nf < 3; ++nf) {
      int n = n0 + wc * 48 + nf * 16 + cc;
      int mb = m0 + (a >> 1) * 64 + wr2 * 32 + (a & 1) * 16 + g * 4;
      float v[4];
#pragma unroll
      for (int j = 0; j < 4; ++j) v[j] = acc[a][nf][j] + bv[nf];
      if (n < 1024) {
#pragma unroll
        for (int j = 0; j < 4; ++j) outq[(size_t)(mb + j) * 1024 + n] = f2bf(v[j]);
      } else {
        int n2 = n - 1024;
        int kv = n2 >> 10; n2 &= 1023;
        int hh = n2 >> 6, d = n2 & 63;
        int bb = mb >> 11, ss = mb & 2047;
        float* pr = outp + ((((size_t)bb * 2 + kv) * 16 + hh) * 2048 + ss) * 64 + d;
#pragma unroll
        for (int j = 0; j < 4; ++j) pr[(size_t)j * 64] = v[j];
      }
    }
}

// ---------------- 128xBN tile MFMA GEMM (m97 structure) — proj only ----------
template <int EPI, int BN>
__global__ __launch_bounds__(256) void k_gemm(
    const u16* __restrict__ A, const u16* __restrict__ Bt,
    const float* __restrict__ bias, u16* __restrict__ outq,
    float* __restrict__ outp, int M, int N, int K) {
  __shared__ u16 a_lds[128 * 64];
  __shared__ u16 b_lds[BN * 64];
  const int t = threadIdx.x;
  const int lane = t & 63, w = t >> 6;

  int m0, n0;
  {
    constexpr int NXT = (EPI == 0) ? 24 : 16;
    constexpr int NCH = (EPI == 0) ? 12 : 8;
    int f = blockIdx.y * NXT + blockIdx.x;
    int xcd = f & 7, idx = f >> 3;
    int mt = (xcd >> 1) * 8 + idx / NCH;
    int nt = (xcd & 1) * NCH + idx % NCH;
    m0 = mt * 128;
    n0 = nt * BN;
  }

  const int srow = t >> 3;
  const int scb = (t & 7) * 16;
  const int ssw = scb ^ ((srow & 7) << 4);
  const size_t pitch = (size_t)K * 2;
  const char* aS = (const char*)A + (size_t)(m0 + srow) * pitch + ssw;
  const char* bS = (const char*)Bt + (size_t)(n0 + srow) * pitch + ssw;
  char* al = (char*)a_lds + t * 16;
  char* bl = (char*)b_lds + t * 16;
  const int wm = (w >> 1) * 64, wn = (w & 1) * (BN / 2);
  const int cc = lane & 15, g = lane >> 4;
  constexpr int NF = BN / 32;

  f32x4 acc[4][NF] = {};

  for (int kt = 0; kt < K; kt += 64) {
    __syncthreads();
#pragma unroll
    for (int i = 0; i < 4; ++i)
      gload_lds16(aS + (size_t)kt * 2 + (size_t)i * 32 * pitch, al + i * 4096);
#pragma unroll
    for (int i = 0; i < BN / 32; ++i)
      gload_lds16(bS + (size_t)kt * 2 + (size_t)i * 32 * pitch, bl + i * 4096);
    __syncthreads();
#pragma unroll
    for (int kk = 0; kk < 2; ++kk) {
      bf16x8 af[4], bf_[NF];
#pragma unroll
      for (int mf = 0; mf < 4; ++mf) {
        int row = wm + mf * 16 + cc;
        af[mf] = *(const bf16x8*)((const char*)a_lds + row * 128 +
                                  ((kk * 64 + g * 16) ^ ((row & 7) << 4)));
      }
#pragma unroll
      for (int nf = 0; nf < NF; ++nf) {
        int row = wn + nf * 16 + cc;
        bf_[nf] = *(const bf16x8*)((const char*)b_lds + row * 128 +
                                   ((kk * 64 + g * 16) ^ ((row & 7) << 4)));
      }
#pragma unroll
      for (int mf = 0; mf < 4; ++mf)
#pragma unroll
        for (int nf = 0; nf < NF; ++nf)
          acc[mf][nf] = __builtin_amdgcn_mfma_f32_16x16x32_bf16(
              af[mf], bf_[nf], acc[mf][nf], 0, 0, 0);
    }
  }

  float bv[NF];
#pragma unroll
  for (int nf = 0; nf < NF; ++nf) bv[nf] = bias[n0 + wn + nf * 16 + cc];

#pragma unroll
  for (int mf = 0; mf < 4; ++mf)
#pragma unroll
    for (int nf = 0; nf < NF; ++nf) {
      int n = n0 + wn + nf * 16 + cc;
      int mb = m0 + wm + mf * 16 + g * 4;
      float v[4];
#pragma unroll
      for (int j = 0; j < 4; ++j) v[j] = acc[mf][nf][j] + bv[nf];
      if (EPI == 1) {
#pragma unroll
        for (int j = 0; j < 4; ++j) outp[(size_t)(mb + j) * N + n] = v[j];
      } else if (n < 1024) {
#pragma unroll
        for (int j = 0; j < 4; ++j) outq[(size_t)(mb + j) * 1024 + n] = f2bf(v[j]);
      } else {
        int n2 = n - 1024;
        int kv = n2 >> 10; n2 &= 1023;
        int hh = n2 >> 6, d = n2 & 63;
        int bb = mb >> 11, ss = mb & 2047;
        float* pr = outp + ((((size_t)bb * 2 + kv) * 16 + hh) * 2048 + ss) * 64 + d;
#pragma unroll
        for (int j = 0; j < 4; ++j) pr[(size_t)j * 64] = v[j];
      }
    }
}

// ---------------- fused sparse attention v3 ----------------
__global__ __launch_bounds__(256) void k_attn(
    const u16* __restrict__ qws, const u16* __restrict__ kbf,
    const u16* __restrict__ vtw, u16* __restrict__ hws) {
  const int qb = blockIdx.x, h = blockIdx.y, b = blockIdx.z;
  const int t = threadIdx.x, lane = t & 63, w = t >> 6;
  const int cc = lane & 15, g = lane >> 4;

  __shared__ u16 k_lds[256 * 64];      // [256 keys][128 B], XOR-swizzled
  __shared__ u16 p_lds[4][32 * 72];    // per-wave P [32 q][144 B]
  __shared__ float rsum[4][32];

  const char* kh = (const char*)kbf + (size_t)(b * 16 + h) * (2048 * 128);
  const char* vh = (const char*)vtw + (size_t)(b * 16 + h) * (64 * 4096);

  {
    int rr = t >> 3, seg = (t & 7) * 16;
#pragma unroll
    for (int i = 0; i < 8; ++i) {
      int r = i * 32 + rr;
      int i2 = r - 128;
      int gr = (r < 128) ? (qb * 128 + r) : ((i2 >> 3) * 128 + 120 + (i2 & 7));
      gload_lds16(kh + (size_t)gr * 128 + (seg ^ ((r & 7) << 4)),
                  (char*)k_lds + i * 4096 + t * 16);
    }
  }

  bf16x8 qf_[2][2];
  {
    const char* qsrc = (const char*)qws +
        (size_t)(b * 2048 + qb * 128 + w * 32 + cc) * 2048 + h * 128 + g * 16;
#pragma unroll
    for (int qf = 0; qf < 2; ++qf)
#pragma unroll
      for (int kk = 0; kk < 2; ++kk)
        qf_[qf][kk] = *(const bf16x8*)(qsrc + (size_t)qf * 16 * 2048 + kk * 64);
  }
  __syncthreads();

  const int nsum = 8 * qb;
  f32x4 o_[2][4] = {};
  float lsum[2] = { 0.f, 0.f };

#pragma unroll 2
  for (int ch = 0; ch < 4; ++ch) {
    f32x4 s[4][2] = {};
#pragma unroll
    for (int kf2 = 0; kf2 < 4; ++kf2) {
      int row = ch * 64 + kf2 * 16 + cc;
      const char* kr = (const char*)k_lds + row * 128;
#pragma unroll
      for (int kk = 0; kk < 2; ++kk) {
        bf16x8 kfr = *(const bf16x8*)(kr + ((kk * 64 + g * 16) ^ ((cc & 7) << 4)));
#pragma unroll
        for (int qf = 0; qf < 2; ++qf)
          s[kf2][qf] = __builtin_amdgcn_mfma_f32_16x16x32_bf16(
              kfr, qf_[qf][kk], s[kf2][qf], 0, 0, 0);
      }
    }
#pragma unroll
    for (int qf = 0; qf < 2; ++qf) {
      int q_local = w * 32 + qf * 16 + cc;
#pragma unroll
      for (int kf2 = 0; kf2 < 4; ++kf2) {
#pragma unroll
        for (int j = 0; j < 4; ++j) {
          int key = ch * 64 + kf2 * 16 + g * 4 + j;
          bool vis = (key < 128) ? (key <= q_local) : (key - 128 < nsum);
          float p = vis ? exp2f(s[kf2][qf][j] * 0.180336884f) : 0.f;
          s[kf2][qf][j] = p;
          lsum[qf] += p;
        }
        u16x4 pw = { f2bf(s[kf2][qf][0]), f2bf(s[kf2][qf][1]),
                     f2bf(s[kf2][qf][2]), f2bf(s[kf2][qf][3]) };
        *(u16x4*)&p_lds[w][(qf * 16 + cc) * 72 + kf2 * 16 + g * 4] = pw;
      }
    }
#pragma unroll
    for (int kk = 0; kk < 2; ++kk) {
      bf16x8 pa[2], vb[4];
#pragma unroll
      for (int mf = 0; mf < 2; ++mf)
        pa[mf] = *(const bf16x8*)((const char*)p_lds[w] +
                                  (mf * 16 + cc) * 144 + kk * 64 + g * 16);
      int cb = (ch < 2) ? (qb * 256 + ch * 128 + kk * 64 + g * 16)
                        : (((ch - 2) * 8 + kk * 4 + g) * 256 + 240);
#pragma unroll
      for (int nf = 0; nf < 4; ++nf)
        vb[nf] = *(const bf16x8*)(vh + (size_t)(nf * 16 + cc) * 4096 + cb);
#pragma unroll
      for (int mf = 0; mf < 2; ++mf)
#pragma unroll
        for (int nf = 0; nf < 4; ++nf)
          o_[mf][nf] = __builtin_amdgcn_mfma_f32_16x16x32_bf16(pa[mf], vb[nf],
                                                               o_[mf][nf], 0, 0, 0);
    }
  }

#pragma unroll
  for (int qf = 0; qf < 2; ++qf) {
    float sum = lsum[qf];
    sum += __shfl_xor(sum, 16);
    sum += __shfl_xor(sum, 32);
    if (g == 0) rsum[w][qf * 16 + cc] = sum;
  }
#pragma unroll
  for (int mf = 0; mf < 2; ++mf)
#pragma unroll
    for (int j = 0; j < 4; ++j) {
      float inv = 1.0f / rsum[w][mf * 16 + g * 4 + j];
      size_t row = (size_t)(b * 2048 + qb * 128 + w * 32 + mf * 16 + g * 4 + j);
#pragma unroll
      for (int nf = 0; nf < 4; ++nf)
        hws[row * 1024 + h * 64 + nf * 16 + cc] = f2bf(o_[mf][nf][j] * inv);
    }
}

extern "C" void kernel_launch(void* const* d_in, const int* in_sizes, int n_in,
                              void* d_out, int out_size, void* d_ws, size_t ws_size,
                              hipStream_t stream) {
  const float* x      = (const float*)d_in[0];  // [2,2048,1024]
  const float* w_attn = (const float*)d_in[1];  // [1024,3072]
  const float* b_attn = (const float*)d_in[2];  // [3072]
  const float* w_proj = (const float*)d_in[3];  // [1024,1024]
  const float* b_proj = (const float*)d_in[4];  // [1024]
  float* h_out   = (float*)d_out;               // 4,194,304 f32
  float* present = (float*)d_out + 4194304;     // [2][2][16][2048][64] f32

  char* ws = (char*)d_ws;
  u16* xbf = (u16*)(ws);                        // 8 MB  [4096][1024] bf16
  u16* qws = (u16*)(ws + (8u << 20));           // 8 MB  [4096][1024] bf16
  u16* wat = (u16*)(ws + (16u << 20));          // 6 MB  [3072][1024] bf16
  u16* wpt = (u16*)(ws + (22u << 20));          // 2 MB  [1024][1024] bf16
  u16* kbf = (u16*)(ws + (24u << 20));          // 8 MB  [2][16][2048][64] bf16
  u16* vtw = (u16*)(ws + (32u << 20));          // 8 MB  [2][16][64][2048] bf16
  u16* hws = xbf;                               // reuse (x dead after QKV GEMM)

  k_prep<<<8192, 256, 0, stream>>>(x, xbf, w_attn, wat, w_proj, wpt);
  k_gemm256<<<dim3(16, 16), 512, 0, stream>>>(xbf, wat, b_attn, qws, present);
  k_kv<<<8192, 256, 0, stream>>>(present, kbf, vtw);
  k_attn<<<dim3(16, 16, 2), 256, 0, stream>>>(qws, kbf, vtw, hws);
  k_gemm<1, 64><<<dim3(16, 32), 256, 0, stream>>>(hws, wpt, b_proj, nullptr,
                                                  h_out, 4096, 1024, 1024);
}

// Round 16
// 86.356 us; speedup vs baseline: 1.0686x; 1.0221x over previous
//
#include <hip/hip_runtime.h>
#include <stdint.h>

typedef unsigned short u16;
typedef unsigned int u32;
typedef __attribute__((ext_vector_type(4))) float f32x4;
typedef __attribute__((ext_vector_type(4))) u16 u16x4;
typedef __attribute__((ext_vector_type(8))) __bf16 bf16x8;

__device__ __forceinline__ u16 f2bf(float f) {
  u32 u = __builtin_bit_cast(u32, f);
  u = (u + 0x7FFFu + ((u >> 16) & 1u)) >> 16;   // RNE
  return (u16)u;
}

__device__ __forceinline__ void gload_lds16(const void* g, void* l) {
  __builtin_amdgcn_global_load_lds(
      (const __attribute__((address_space(1))) void*)(uintptr_t)(g),
      (__attribute__((address_space(3))) void*)(u32)(uintptr_t)(l),
      16, 0, 0);
}

// ---- fused prep: x cvt (blocks 0..4095), w_attn^T (4096..7167), w_proj^T ----
__global__ __launch_bounds__(256) void k_prep(
    const float* __restrict__ x, u16* __restrict__ xbf,
    const float* __restrict__ wa, u16* __restrict__ wat,
    const float* __restrict__ wp, u16* __restrict__ wpt) {
  __shared__ float tile[32][33];
  const int bid = blockIdx.x, t = threadIdx.x;
  if (bid < 4096) {
    int i = bid * 256 + t;
    f32x4 v = ((const f32x4*)x)[i];
    u16x4 o = { f2bf(v.x), f2bf(v.y), f2bf(v.z), f2bf(v.w) };
    ((u16x4*)xbf)[i] = o;
    return;
  }
  const float* in;
  u16* out;
  int n0, k0, N;
  if (bid < 4096 + 3072) {
    int idx = bid - 4096;
    in = wa; out = wat; N = 3072;
    n0 = (idx % 96) * 32; k0 = (idx / 96) * 32;
  } else {
    int idx = bid - 7168;
    in = wp; out = wpt; N = 1024;
    n0 = (idx & 31) * 32; k0 = (idx >> 5) * 32;
  }
  int c = t & 31, r0 = t >> 5;
#pragma unroll
  for (int i = 0; i < 4; ++i)
    tile[r0 + i * 8][c] = in[(size_t)(k0 + r0 + i * 8) * N + n0 + c];
  __syncthreads();
  int on = t >> 3, ok = (t & 7) * 4;
  u16x4 o = { f2bf(tile[ok + 0][on]), f2bf(tile[ok + 1][on]),
              f2bf(tile[ok + 2][on]), f2bf(tile[ok + 3][on]) };
  *(u16x4*)&out[(size_t)(n0 + on) * 1024 + k0 + ok] = o;
}

// ---- k_kv: blocks 0..4095 = V^T tiles (f32->bf16), 4096..8191 = K cvt ----
__global__ __launch_bounds__(256) void k_kv(const float* __restrict__ present,
                                            u16* __restrict__ kbf,
                                            u16* __restrict__ vtw) {
  __shared__ float tile[32][33];
  const int bid = blockIdx.x, t = threadIdx.x;
  if (bid >= 4096) {
    int i = bid - 4096;
    size_t idx = (size_t)i * 256 + t;           // f32x4 index into K halves
    size_t b = idx >> 19, off = idx & ((1u << 19) - 1);
    f32x4 v = ((const f32x4*)present)[b * (1u << 20) + off];
    u16x4 o = { f2bf(v.x), f2bf(v.y), f2bf(v.z), f2bf(v.w) };
    ((u16x4*)kbf)[idx] = o;
    return;
  }
  int bh = bid >> 7, rem = bid & 127;
  int s0 = (rem >> 1) * 32, d0 = (rem & 1) * 32;
  int b = bh >> 4, h = bh & 15;
  const float* vsrc = present + (((size_t)(b * 2 + 1) * 16 + h) * 2048) * 64;
  u16* vdst = vtw + ((size_t)bh * 64) * 2048;
  int c = t & 31, r0 = t >> 5;
#pragma unroll
  for (int i = 0; i < 4; ++i)
    tile[r0 + i * 8][c] = vsrc[(size_t)(s0 + r0 + i * 8) * 64 + d0 + c];
  __syncthreads();
  int on = t >> 3, ok = (t & 7) * 4;
  u16x4 o = { f2bf(tile[ok + 0][on]), f2bf(tile[ok + 1][on]),
              f2bf(tile[ok + 2][on]), f2bf(tile[ok + 3][on]) };
  *(u16x4*)&vdst[(size_t)(d0 + on) * 2048 + s0 + ok] = o;
}

// ======== 256x192 read-ahead GEMM for QKV (M=4096,N=3072,K=1024) ========
// Session-best configuration (round 13, 86.5 us total). 512 thr = 8 waves
// (4M x 2N), per-wave 64x96. Two named frag sets: set1's ds_reads issue
// BEFORE MFMA(set0); next tile's set0 reads issue right after the
// end-of-tile fence. Single fused {vmcnt(0) lgkmcnt(0); s_barrier} fence per
// K-tile (memory clobber; round-5 race discipline). Structural note: seven
// schedule variants (2-bar, counted-vmcnt dbuf, coarse/fine phase-split,
// read-ahead, BK=128, 1-3 blk/CU) all land at 46-50 us, MfmaUtil ~20% —
// short-K (16-step) plateau of this kernel family at this shape.
__global__ __launch_bounds__(512, 1) void k_gemm256(
    const u16* __restrict__ A, const u16* __restrict__ Bt,
    const float* __restrict__ bias, u16* __restrict__ outq,
    float* __restrict__ outp) {
  __shared__ u16 a_lds[2][256 * 64];
  __shared__ u16 b_lds[2][192 * 64];
  const int t = threadIdx.x;
  const int lane = t & 63, w = t >> 6;
  const int cc = lane & 15, g = lane >> 4;
  const int wr = w >> 1, wc = w & 1;          // 4M x 2N wave grid

  int f = blockIdx.y * 16 + blockIdx.x;       // 256 blocks = 1/CU
  int xcd = f & 7, idx = f >> 3;
  const int m0 = ((xcd >> 1) * 4 + (idx >> 3)) * 256;
  const int n0 = ((xcd & 1) * 8 + (idx & 7)) * 192;

  const int srow = t >> 3;                    // 0..63
  const int scolb = (t & 7) * 16;
  const size_t pitch = 2048;                  // K*2 bytes

  auto stage = [&](int bi, int kt) {
#pragma unroll
    for (int i = 0; i < 3; ++i) {
      int row = i * 64 + srow;
      gload_lds16((const char*)Bt + (size_t)(n0 + row) * pitch + kt * 128 +
                      (scolb ^ ((row & 7) << 4)),
                  (char*)b_lds[bi] + row * 128 + scolb);
    }
#pragma unroll
    for (int i = 0; i < 4; ++i) {
      int row = i * 64 + srow;
      gload_lds16((const char*)A + (size_t)(m0 + row) * pitch + kt * 128 +
                      (scolb ^ ((row & 7) << 4)),
                  (char*)a_lds[bi] + row * 128 + scolb);
    }
  };

  auto readA = [&](bf16x8 (&af)[4], int bi, int kk) {
#pragma unroll
    for (int mf = 0; mf < 4; ++mf) {
      int row = wr * 64 + mf * 16 + cc;
      af[mf] = *(const bf16x8*)((const char*)a_lds[bi] + row * 128 +
                                ((kk * 64 + g * 16) ^ ((row & 7) << 4)));
    }
  };
  auto readB = [&](bf16x8 (&bf)[6], int bi, int kk) {
#pragma unroll
    for (int nf = 0; nf < 6; ++nf) {
      int row = wc * 96 + nf * 16 + cc;
      bf[nf] = *(const bf16x8*)((const char*)b_lds[bi] + row * 128 +
                                ((kk * 64 + g * 16) ^ ((row & 7) << 4)));
    }
  };

  f32x4 acc[4][6] = {};
  bf16x8 a0[4], b0[6], a1[4], b1[6];

  stage(0, 0);
  asm volatile("s_waitcnt vmcnt(0)\n\ts_barrier" ::: "memory");
  readA(a0, 0, 0);
  readB(b0, 0, 0);

  for (int j = 0; j < 16; ++j) {
    const int bi = j & 1, nx = bi ^ 1;
    if (j < 15) stage(nx, j + 1);            // 7 loads, fly across compute
    readA(a1, bi, 1);                        // set1 issue (overlaps set0 MFMA)
    readB(b1, bi, 1);

    __builtin_amdgcn_s_setprio(1);
#pragma unroll
    for (int mf = 0; mf < 4; ++mf)
#pragma unroll
      for (int nf = 0; nf < 6; ++nf)
        acc[mf][nf] = __builtin_amdgcn_mfma_f32_16x16x32_bf16(
            a0[mf], b0[nf], acc[mf][nf], 0, 0, 0);
    __builtin_amdgcn_s_setprio(0);

    __builtin_amdgcn_s_setprio(1);
#pragma unroll
    for (int mf = 0; mf < 4; ++mf)
#pragma unroll
      for (int nf = 0; nf < 6; ++nf)
        acc[mf][nf] = __builtin_amdgcn_mfma_f32_16x16x32_bf16(
            a1[mf], b1[nf], acc[mf][nf], 0, 0, 0);
    __builtin_amdgcn_s_setprio(0);

    if (j < 15) {
      asm volatile("s_waitcnt vmcnt(0) lgkmcnt(0)\n\ts_barrier" ::: "memory");
      readA(a0, nx, 0);                      // next-tile set0 (read-ahead)
      readB(b0, nx, 0);
    }
  }

  float bv[6];
#pragma unroll
  for (int nf = 0; nf < 6; ++nf) bv[nf] = bias[n0 + wc * 96 + nf * 16 + cc];

#pragma unroll
  for (int mf = 0; mf < 4; ++mf)
#pragma unroll
    for (int nf = 0; nf < 6; ++nf) {
      int n = n0 + wc * 96 + nf * 16 + cc;
      int mb = m0 + wr * 64 + mf * 16 + g * 4;
      float v[4];
#pragma unroll
      for (int j = 0; j < 4; ++j) v[j] = acc[mf][nf][j] + bv[nf];
      if (n < 1024) {
#pragma unroll
        for (int j = 0; j < 4; ++j) outq[(size_t)(mb + j) * 1024 + n] = f2bf(v[j]);
      } else {
        int n2 = n - 1024;
        int kv = n2 >> 10; n2 &= 1023;
        int hh = n2 >> 6, d = n2 & 63;
        int bb = mb >> 11, ss = mb & 2047;
        float* pr = outp + ((((size_t)bb * 2 + kv) * 16 + hh) * 2048 + ss) * 64 + d;
#pragma unroll
        for (int j = 0; j < 4; ++j) pr[(size_t)j * 64] = v[j];
      }
    }
}

// ---------------- 128xBN tile MFMA GEMM (m97 structure) — proj only ----------
template <int EPI, int BN>
__global__ __launch_bounds__(256) void k_gemm(
    const u16* __restrict__ A, const u16* __restrict__ Bt,
    const float* __restrict__ bias, u16* __restrict__ outq,
    float* __restrict__ outp, int M, int N, int K) {
  __shared__ u16 a_lds[128 * 64];
  __shared__ u16 b_lds[BN * 64];
  const int t = threadIdx.x;
  const int lane = t & 63, w = t >> 6;

  int m0, n0;
  {
    constexpr int NXT = (EPI == 0) ? 24 : 16;
    constexpr int NCH = (EPI == 0) ? 12 : 8;
    int f = blockIdx.y * NXT + blockIdx.x;
    int xcd = f & 7, idx = f >> 3;
    int mt = (xcd >> 1) * 8 + idx / NCH;
    int nt = (xcd & 1) * NCH + idx % NCH;
    m0 = mt * 128;
    n0 = nt * BN;
  }

  const int srow = t >> 3;
  const int scb = (t & 7) * 16;
  const int ssw = scb ^ ((srow & 7) << 4);
  const size_t pitch = (size_t)K * 2;
  const char* aS = (const char*)A + (size_t)(m0 + srow) * pitch + ssw;
  const char* bS = (const char*)Bt + (size_t)(n0 + srow) * pitch + ssw;
  char* al = (char*)a_lds + t * 16;
  char* bl = (char*)b_lds + t * 16;
  const int wm = (w >> 1) * 64, wn = (w & 1) * (BN / 2);
  const int cc = lane & 15, g = lane >> 4;
  constexpr int NF = BN / 32;

  f32x4 acc[4][NF] = {};

  for (int kt = 0; kt < K; kt += 64) {
    __syncthreads();
#pragma unroll
    for (int i = 0; i < 4; ++i)
      gload_lds16(aS + (size_t)kt * 2 + (size_t)i * 32 * pitch, al + i * 4096);
#pragma unroll
    for (int i = 0; i < BN / 32; ++i)
      gload_lds16(bS + (size_t)kt * 2 + (size_t)i * 32 * pitch, bl + i * 4096);
    __syncthreads();
#pragma unroll
    for (int kk = 0; kk < 2; ++kk) {
      bf16x8 af[4], bf_[NF];
#pragma unroll
      for (int mf = 0; mf < 4; ++mf) {
        int row = wm + mf * 16 + cc;
        af[mf] = *(const bf16x8*)((const char*)a_lds + row * 128 +
                                  ((kk * 64 + g * 16) ^ ((row & 7) << 4)));
      }
#pragma unroll
      for (int nf = 0; nf < NF; ++nf) {
        int row = wn + nf * 16 + cc;
        bf_[nf] = *(const bf16x8*)((const char*)b_lds + row * 128 +
                                   ((kk * 64 + g * 16) ^ ((row & 7) << 4)));
      }
#pragma unroll
      for (int mf = 0; mf < 4; ++mf)
#pragma unroll
        for (int nf = 0; nf < NF; ++nf)
          acc[mf][nf] = __builtin_amdgcn_mfma_f32_16x16x32_bf16(
              af[mf], bf_[nf], acc[mf][nf], 0, 0, 0);
    }
  }

  float bv[NF];
#pragma unroll
  for (int nf = 0; nf < NF; ++nf) bv[nf] = bias[n0 + wn + nf * 16 + cc];

#pragma unroll
  for (int mf = 0; mf < 4; ++mf)
#pragma unroll
    for (int nf = 0; nf < NF; ++nf) {
      int n = n0 + wn + nf * 16 + cc;
      int mb = m0 + wm + mf * 16 + g * 4;
      float v[4];
#pragma unroll
      for (int j = 0; j < 4; ++j) v[j] = acc[mf][nf][j] + bv[nf];
      if (EPI == 1) {
#pragma unroll
        for (int j = 0; j < 4; ++j) outp[(size_t)(mb + j) * N + n] = v[j];
      } else if (n < 1024) {
#pragma unroll
        for (int j = 0; j < 4; ++j) outq[(size_t)(mb + j) * 1024 + n] = f2bf(v[j]);
      } else {
        int n2 = n - 1024;
        int kv = n2 >> 10; n2 &= 1023;
        int hh = n2 >> 6, d = n2 & 63;
        int bb = mb >> 11, ss = mb & 2047;
        float* pr = outp + ((((size_t)bb * 2 + kv) * 16 + hh) * 2048 + ss) * 64 + d;
#pragma unroll
        for (int j = 0; j < 4; ++j) pr[(size_t)j * 64] = v[j];
      }
    }
}

// ---------------- fused sparse attention v3 ----------------
__global__ __launch_bounds__(256) void k_attn(
    const u16* __restrict__ qws, const u16* __restrict__ kbf,
    const u16* __restrict__ vtw, u16* __restrict__ hws) {
  const int qb = blockIdx.x, h = blockIdx.y, b = blockIdx.z;
  const int t = threadIdx.x, lane = t & 63, w = t >> 6;
  const int cc = lane & 15, g = lane >> 4;

  __shared__ u16 k_lds[256 * 64];      // [256 keys][128 B], XOR-swizzled
  __shared__ u16 p_lds[4][32 * 72];    // per-wave P [32 q][144 B]
  __shared__ float rsum[4][32];

  const char* kh = (const char*)kbf + (size_t)(b * 16 + h) * (2048 * 128);
  const char* vh = (const char*)vtw + (size_t)(b * 16 + h) * (64 * 4096);

  {
    int rr = t >> 3, seg = (t & 7) * 16;
#pragma unroll
    for (int i = 0; i < 8; ++i) {
      int r = i * 32 + rr;
      int i2 = r - 128;
      int gr = (r < 128) ? (qb * 128 + r) : ((i2 >> 3) * 128 + 120 + (i2 & 7));
      gload_lds16(kh + (size_t)gr * 128 + (seg ^ ((r & 7) << 4)),
                  (char*)k_lds + i * 4096 + t * 16);
    }
  }

  bf16x8 qf_[2][2];
  {
    const char* qsrc = (const char*)qws +
        (size_t)(b * 2048 + qb * 128 + w * 32 + cc) * 2048 + h * 128 + g * 16;
#pragma unroll
    for (int qf = 0; qf < 2; ++qf)
#pragma unroll
      for (int kk = 0; kk < 2; ++kk)
        qf_[qf][kk] = *(const bf16x8*)(qsrc + (size_t)qf * 16 * 2048 + kk * 64);
  }
  __syncthreads();

  const int nsum = 8 * qb;
  f32x4 o_[2][4] = {};
  float lsum[2] = { 0.f, 0.f };

#pragma unroll 2
  for (int ch = 0; ch < 4; ++ch) {
    f32x4 s[4][2] = {};
#pragma unroll
    for (int kf2 = 0; kf2 < 4; ++kf2) {
      int row = ch * 64 + kf2 * 16 + cc;
      const char* kr = (const char*)k_lds + row * 128;
#pragma unroll
      for (int kk = 0; kk < 2; ++kk) {
        bf16x8 kfr = *(const bf16x8*)(kr + ((kk * 64 + g * 16) ^ ((cc & 7) << 4)));
#pragma unroll
        for (int qf = 0; qf < 2; ++qf)
          s[kf2][qf] = __builtin_amdgcn_mfma_f32_16x16x32_bf16(
              kfr, qf_[qf][kk], s[kf2][qf], 0, 0, 0);
      }
    }
#pragma unroll
    for (int qf = 0; qf < 2; ++qf) {
      int q_local = w * 32 + qf * 16 + cc;
#pragma unroll
      for (int kf2 = 0; kf2 < 4; ++kf2) {
#pragma unroll
        for (int j = 0; j < 4; ++j) {
          int key = ch * 64 + kf2 * 16 + g * 4 + j;
          bool vis = (key < 128) ? (key <= q_local) : (key - 128 < nsum);
          float p = vis ? exp2f(s[kf2][qf][j] * 0.180336884f) : 0.f;
          s[kf2][qf][j] = p;
          lsum[qf] += p;
        }
        u16x4 pw = { f2bf(s[kf2][qf][0]), f2bf(s[kf2][qf][1]),
                     f2bf(s[kf2][qf][2]), f2bf(s[kf2][qf][3]) };
        *(u16x4*)&p_lds[w][(qf * 16 + cc) * 72 + kf2 * 16 + g * 4] = pw;
      }
    }
#pragma unroll
    for (int kk = 0; kk < 2; ++kk) {
      bf16x8 pa[2], vb[4];
#pragma unroll
      for (int mf = 0; mf < 2; ++mf)
        pa[mf] = *(const bf16x8*)((const char*)p_lds[w] +
                                  (mf * 16 + cc) * 144 + kk * 64 + g * 16);
      int cb = (ch < 2) ? (qb * 256 + ch * 128 + kk * 64 + g * 16)
                        : (((ch - 2) * 8 + kk * 4 + g) * 256 + 240);
#pragma unroll
      for (int nf = 0; nf < 4; ++nf)
        vb[nf] = *(const bf16x8*)(vh + (size_t)(nf * 16 + cc) * 4096 + cb);
#pragma unroll
      for (int mf = 0; mf < 2; ++mf)
#pragma unroll
        for (int nf = 0; nf < 4; ++nf)
          o_[mf][nf] = __builtin_amdgcn_mfma_f32_16x16x32_bf16(pa[mf], vb[nf],
                                                               o_[mf][nf], 0, 0, 0);
    }
  }

#pragma unroll
  for (int qf = 0; qf < 2; ++qf) {
    float sum = lsum[qf];
    sum += __shfl_xor(sum, 16);
    sum += __shfl_xor(sum, 32);
    if (g == 0) rsum[w][qf * 16 + cc] = sum;
  }
#pragma unroll
  for (int mf = 0; mf < 2; ++mf)
#pragma unroll
    for (int j = 0; j < 4; ++j) {
      float inv = 1.0f / rsum[w][mf * 16 + g * 4 + j];
      size_t row = (size_t)(b * 2048 + qb * 128 + w * 32 + mf * 16 + g * 4 + j);
#pragma unroll
      for (int nf = 0; nf < 4; ++nf)
        hws[row * 1024 + h * 64 + nf * 16 + cc] = f2bf(o_[mf][nf][j] * inv);
    }
}

extern "C" void kernel_launch(void* const* d_in, const int* in_sizes, int n_in,
                              void* d_out, int out_size, void* d_ws, size_t ws_size,
                              hipStream_t stream) {
  const float* x      = (const float*)d_in[0];  // [2,2048,1024]
  const float* w_attn = (const float*)d_in[1];  // [1024,3072]
  const float* b_attn = (const float*)d_in[2];  // [3072]
  const float* w_proj = (const float*)d_in[3];  // [1024,1024]
  const float* b_proj = (const float*)d_in[4];  // [1024]
  float* h_out   = (float*)d_out;               // 4,194,304 f32
  float* present = (float*)d_out + 4194304;     // [2][2][16][2048][64] f32

  char* ws = (char*)d_ws;
  u16* xbf = (u16*)(ws);                        // 8 MB  [4096][1024] bf16
  u16* qws = (u16*)(ws + (8u << 20));           // 8 MB  [4096][1024] bf16
  u16* wat = (u16*)(ws + (16u << 20));          // 6 MB  [3072][1024] bf16
  u16* wpt = (u16*)(ws + (22u << 20));          // 2 MB  [1024][1024] bf16
  u16* kbf = (u16*)(ws + (24u << 20));          // 8 MB  [2][16][2048][64] bf16
  u16* vtw = (u16*)(ws + (32u << 20));          // 8 MB  [2][16][64][2048] bf16
  u16* hws = xbf;                               // reuse (x dead after QKV GEMM)

  k_prep<<<8192, 256, 0, stream>>>(x, xbf, w_attn, wat, w_proj, wpt);
  k_gemm256<<<dim3(16, 16), 512, 0, stream>>>(xbf, wat, b_attn, qws, present);
  k_kv<<<8192, 256, 0, stream>>>(present, kbf, vtw);
  k_attn<<<dim3(16, 16, 2), 256, 0, stream>>>(qws, kbf, vtw, hws);
  k_gemm<1, 64><<<dim3(16, 32), 256, 0, stream>>>(hws, wpt, b_proj, nullptr,
                                                  h_out, 4096, 1024, 1024);
}